// Round 2
// baseline (353.854 us; speedup 1.0000x reference)
//
#include <hip/hip_runtime.h>
#include <hip/hip_bf16.h>

// MultiHeadAttentionBlock on MI355X (gfx950), bf16 MFMA pipeline.
// B=2, L=2048, D=1024, H=16, DK=64.
//
// ws footprint: 32 MiB exactly (qkv 24 MiB + attnout 8 MiB). f32->bf16 casts
// are fused into GEMM staging (no separate cast buffers) to stay within ws.

#define DEVINL __device__ __forceinline__

typedef __attribute__((ext_vector_type(8))) short short8;   // 8 x bf16 bits (4 VGPR)
typedef __attribute__((ext_vector_type(4))) float floatx4;  // MFMA C/D frag

static constexpr int Bq = 2, Lq = 2048, Dm = 1024;
static constexpr int Mrows = Bq * Lq;            // 4096
static constexpr size_t QKV_LD = 3072;           // packed Q|K|V row stride

DEVINL unsigned short f2bf(float x) {
  __hip_bfloat16 h = __float2bfloat16(x);
  unsigned short u;
  __builtin_memcpy(&u, &h, 2);
  return u;
}

DEVINL short8 cvt8(float4 a, float4 b) {
  union { unsigned short u[8]; short8 v; } o;
  o.u[0] = f2bf(a.x); o.u[1] = f2bf(a.y); o.u[2] = f2bf(a.z); o.u[3] = f2bf(a.w);
  o.u[4] = f2bf(b.x); o.u[5] = f2bf(b.y); o.u[6] = f2bf(b.z); o.u[7] = f2bf(b.w);
  return o.v;
}

// async 16B global -> LDS (wave-uniform LDS base + lane*16; global addr per-lane)
DEVINL void gll16(const void* g, const void* l) {
  auto gp = (const __attribute__((address_space(1))) char*)(unsigned long long)(uintptr_t)g;
  auto lp = (__attribute__((address_space(3))) char*)(unsigned int)(uintptr_t)l;
  __builtin_amdgcn_global_load_lds(gp, lp, 16, 0, 0);
}

// ---------------- GEMM: C = A @ W^T + bias ----------------
// A: (M,K) bf16 (A_BF16) or f32; W: (N,K) f32 (converted in staging).
// 128x128 tile, BK=32, 4 waves each owning 64x64, 16x16x32 bf16 MFMA.
// LDS tiles [128][32] bf16, 16B-granule XOR swizzle (granule ^= row&3).
template <bool A_BF16, bool OUT_BF16>
__global__ __launch_bounds__(256) void gemm_k(
    const void* __restrict__ A0, const void* __restrict__ A1, const void* __restrict__ A2,
    const float* __restrict__ W0, const float* __restrict__ W1, const float* __restrict__ W2,
    const float* __restrict__ b0, const float* __restrict__ b1, const float* __restrict__ b2,
    void* __restrict__ Cout, int M, int N, int K, int ldc) {
  const int z = blockIdx.z;
  const void* Aany = (z == 0) ? A0 : ((z == 1) ? A1 : A2);
  const float* W = (z == 0) ? W0 : ((z == 1) ? W1 : W2);
  const float* bias = (z == 0) ? b0 : ((z == 1) ? b1 : b2);
  const int m0 = blockIdx.x * 128, n0 = blockIdx.y * 128;
  const int tid = threadIdx.x, lane = tid & 63, w = tid >> 6;
  const int wr = w >> 1, wc = w & 1;

  __shared__ __align__(16) unsigned short As[128 * 32];
  __shared__ __align__(16) unsigned short Bs[128 * 32];

  floatx4 acc[4][4] = {};

  float4 wreg[2][2];
  float4 areg[2][2];

  auto loadW = [&](int kt) {
#pragma unroll
    for (int it = 0; it < 2; ++it) {
      int g = it * 256 + tid, row = g >> 2, gk = g & 3;
      const float* p = W + (size_t)(n0 + row) * K + kt + gk * 8;
      wreg[it][0] = ((const float4*)p)[0];
      wreg[it][1] = ((const float4*)p)[1];
    }
  };
  auto loadA = [&](int kt) {
#pragma unroll
    for (int it = 0; it < 2; ++it) {
      int g = it * 256 + tid, row = g >> 2, gk = g & 3;
      const float* p = (const float*)Aany + (size_t)(m0 + row) * K + kt + gk * 8;
      areg[it][0] = ((const float4*)p)[0];
      areg[it][1] = ((const float4*)p)[1];
    }
  };

  loadW(0);
  if (!A_BF16) loadA(0);

  const int krow = lane >> 4;  // 16B granule index (0..3) along K
  for (int kt = 0; kt < K; kt += 32) {
    __syncthreads();
#pragma unroll
    for (int it = 0; it < 2; ++it) {
      int g = it * 256 + tid, row = g >> 2, gk = g & 3;
      int dst = row * 64 + ((gk ^ (row & 3)) << 4);
      if (!A_BF16) *(short8*)((char*)As + dst) = cvt8(areg[it][0], areg[it][1]);
      *(short8*)((char*)Bs + dst) = cvt8(wreg[it][0], wreg[it][1]);
    }
    if (A_BF16) {
#pragma unroll
      for (int it = 0; it < 2; ++it) {
        int g = it * 256 + tid, row = g >> 2, gk = g & 3;
        int koff = (gk ^ (row & 3)) * 8;
        gll16((const unsigned short*)Aany + (size_t)(m0 + row) * K + kt + koff,
              (const char*)As + (it * 256 + w * 64) * 16);
      }
    }
    if (kt + 32 < K) {
      loadW(kt + 32);
      if (!A_BF16) loadA(kt + 32);
    }
    __syncthreads();

    short8 af[4], bf[4];
#pragma unroll
    for (int m = 0; m < 4; ++m) {
      int row = wr * 64 + m * 16 + (lane & 15);
      af[m] = *(const short8*)((const char*)As + row * 64 + ((krow ^ (row & 3)) << 4));
    }
#pragma unroll
    for (int n = 0; n < 4; ++n) {
      int row = wc * 64 + n * 16 + (lane & 15);
      bf[n] = *(const short8*)((const char*)Bs + row * 64 + ((krow ^ (row & 3)) << 4));
    }
#pragma unroll
    for (int m = 0; m < 4; ++m)
#pragma unroll
      for (int n = 0; n < 4; ++n)
        acc[m][n] = __builtin_amdgcn_mfma_f32_16x16x32_bf16(af[m], bf[n], acc[m][n], 0, 0, 0);
  }

  const int r4 = lane >> 4;
#pragma unroll
  for (int m = 0; m < 4; ++m)
#pragma unroll
    for (int n = 0; n < 4; ++n) {
      int col = n0 + wc * 64 + n * 16 + (lane & 15);
      float bv = bias[col];
#pragma unroll
      for (int r = 0; r < 4; ++r) {
        int row = m0 + wr * 64 + m * 16 + r4 * 4 + r;
        float v = acc[m][n][r] + bv;
        if (OUT_BF16)
          ((unsigned short*)Cout)[(size_t)row * ldc + (size_t)z * N + col] = f2bf(v);
        else
          ((float*)Cout)[(size_t)row * ldc + (size_t)z * N + col] = v;
      }
    }
}

// ---------------- flash attention ----------------
// grid: (L/64, B*H). 256 threads = 4 waves; wave w owns q rows [q0+16w, q0+16w+16).
__global__ __launch_bounds__(256) void attn_kernel(const unsigned short* __restrict__ QKV,
                                                   const int* __restrict__ mask,
                                                   unsigned short* __restrict__ Aout) {
  const int bh = blockIdx.y, b = bh >> 4, h = bh & 15;
  const int q0 = blockIdx.x * 64;
  const int tid = threadIdx.x, lane = tid & 63, w = tid >> 6;

  __shared__ __align__(16) unsigned short Klds[64 * 64];
  __shared__ __align__(16) unsigned short Vtlds[64 * 64];
  __shared__ __align__(16) unsigned short Plds[4][16 * 72];  // rows padded to 72 bf16

  const unsigned short* base = QKV + (size_t)b * Lq * QKV_LD;

  // Q fragments (A-operand): row = lane&15 within wave's 16 rows, k = c*32 + (lane>>4)*8
  short8 qf[2];
  {
    int row = q0 + w * 16 + (lane & 15);
#pragma unroll
    for (int c = 0; c < 2; ++c)
      qf[c] = *(const short8*)(base + (size_t)row * QKV_LD + h * 64 + c * 32 + (lane >> 4) * 8);
  }

  floatx4 o[4] = {};
  float mrow[4], lrow[4];
#pragma unroll
  for (int r = 0; r < 4; ++r) { mrow[r] = -1e30f; lrow[r] = 0.f; }

  for (int t = 0; t < Lq / 64; ++t) {
    const int k0 = t * 64;
    __syncthreads();
    // stage K tile [64 keys][64 dk] with read-swizzle-compensated source
#pragma unroll
    for (int it = 0; it < 2; ++it) {
      int g = it * 256 + tid;
      int key = g >> 3, gk = g & 7;
      int dkoff = (gk ^ (key & 7)) * 8;
      gll16(base + (size_t)(k0 + key) * QKV_LD + 1024 + h * 64 + dkoff,
            (const char*)Klds + (it * 256 + w * 64) * 16);
    }
    // stage V transposed: Vt[d][key], off = d*128 + ((key>>3)^(d&7))*16 + (key&7)*2
#pragma unroll
    for (int rep = 0; rep < 2; ++rep) {
      int g = rep * 256 + tid;
      int key = g >> 3, d0 = (g & 7) * 8;
      short8 vv = *(const short8*)(base + (size_t)(k0 + key) * QKV_LD + 2048 + h * 64 + d0);
#pragma unroll
      for (int i2 = 0; i2 < 8; ++i2) {
        int d = d0 + i2;
        int off = d * 128 + (((key >> 3) ^ i2) << 4) + ((key & 7) * 2);
        *(unsigned short*)((char*)Vtlds + off) = (unsigned short)vv[i2];
      }
    }
    __syncthreads();

    // S = Q K^T (per wave: 16 q x 64 keys)
    floatx4 s[4] = {};
#pragma unroll
    for (int f = 0; f < 4; ++f) {
      int key = f * 16 + (lane & 15);
#pragma unroll
      for (int c = 0; c < 2; ++c) {
        short8 kf = *(const short8*)((const char*)Klds + key * 128 +
                                     (((c * 4 + (lane >> 4)) ^ (key & 7)) << 4));
        s[f] = __builtin_amdgcn_mfma_f32_16x16x32_bf16(qf[c], kf, s[f], 0, 0, 0);
      }
    }

    // scale + mask + online softmax
    float tmax[4] = {-1e30f, -1e30f, -1e30f, -1e30f};
#pragma unroll
    for (int f = 0; f < 4; ++f) {
      int mv = mask[b * Lq + k0 + f * 16 + (lane & 15)];
#pragma unroll
      for (int r = 0; r < 4; ++r) {
        float sv = s[f][r] * 0.125f;
        sv = mv ? sv : -1e9f;
        s[f][r] = sv;
        tmax[r] = fmaxf(tmax[r], sv);
      }
    }
#pragma unroll
    for (int dx = 1; dx <= 8; dx <<= 1)
#pragma unroll
      for (int r = 0; r < 4; ++r) tmax[r] = fmaxf(tmax[r], __shfl_xor(tmax[r], dx, 64));

    float mnew[4], alpha[4], rsum[4] = {0, 0, 0, 0};
#pragma unroll
    for (int r = 0; r < 4; ++r) {
      mnew[r] = fmaxf(mrow[r], tmax[r]);
      alpha[r] = __expf(mrow[r] - mnew[r]);
      mrow[r] = mnew[r];
    }
#pragma unroll
    for (int f = 0; f < 4; ++f)
#pragma unroll
      for (int r = 0; r < 4; ++r) {
        float p = __expf(s[f][r] - mnew[r]);
        s[f][r] = p;
        rsum[r] += p;
      }
#pragma unroll
    for (int dx = 1; dx <= 8; dx <<= 1)
#pragma unroll
      for (int r = 0; r < 4; ++r) rsum[r] += __shfl_xor(rsum[r], dx, 64);
#pragma unroll
    for (int r = 0; r < 4; ++r) lrow[r] = lrow[r] * alpha[r] + rsum[r];
#pragma unroll
    for (int df = 0; df < 4; ++df)
#pragma unroll
      for (int r = 0; r < 4; ++r) o[df][r] *= alpha[r];

    // P -> LDS (bf16), rows padded to 72
#pragma unroll
    for (int f = 0; f < 4; ++f)
#pragma unroll
      for (int r = 0; r < 4; ++r) {
        int row = (lane >> 4) * 4 + r, col = f * 16 + (lane & 15);
        Plds[w][row * 72 + col] = f2bf(s[f][r]);
      }

    // O += P @ V
    short8 pf[2];
#pragma unroll
    for (int kc = 0; kc < 2; ++kc)
      pf[kc] = *(const short8*)((const char*)&Plds[w][0] + (lane & 15) * 144 + kc * 64 +
                                (lane >> 4) * 16);
#pragma unroll
    for (int df = 0; df < 4; ++df) {
      int d = df * 16 + (lane & 15);
#pragma unroll
      for (int kc = 0; kc < 2; ++kc) {
        short8 vf = *(const short8*)((const char*)Vtlds + d * 128 +
                                     (((kc * 4 + (lane >> 4)) ^ (lane & 7)) << 4));
        o[df] = __builtin_amdgcn_mfma_f32_16x16x32_bf16(pf[kc], vf, o[df], 0, 0, 0);
      }
    }
  }

  // normalize + store bf16
#pragma unroll
  for (int df = 0; df < 4; ++df)
#pragma unroll
    for (int r = 0; r < 4; ++r) {
      int row = q0 + w * 16 + (lane >> 4) * 4 + r;
      int col = h * 64 + df * 16 + (lane & 15);
      Aout[(size_t)(b * Lq + row) * Dm + col] = f2bf(o[df][r] / lrow[r]);
    }
}

// ---------------- launcher ----------------
extern "C" void kernel_launch(void* const* d_in, const int* in_sizes, int n_in,
                              void* d_out, int out_size, void* d_ws, size_t ws_size,
                              hipStream_t stream) {
  const float* q = (const float*)d_in[0];
  const float* k = (const float*)d_in[1];
  const float* v = (const float*)d_in[2];
  const int* maskp = (const int*)d_in[3];
  const float* wq = (const float*)d_in[4];
  const float* bq = (const float*)d_in[5];
  const float* wk = (const float*)d_in[6];
  const float* bk = (const float*)d_in[7];
  const float* wv = (const float*)d_in[8];
  const float* bv = (const float*)d_in[9];
  const float* wo = (const float*)d_in[10];
  const float* bo = (const float*)d_in[11];

  unsigned short* qkv = (unsigned short*)d_ws;             // 4096*3072 bf16 = 24 MiB
  unsigned short* attnout = qkv + (size_t)Mrows * QKV_LD;  // 4096*1024 bf16 =  8 MiB
  // total ws use: 32 MiB

  // QKV projections: qkv[:, z*1024 + n] = in_z @ w_z^T + b_z (bf16 out, ldc 3072)
  gemm_k<false, true><<<dim3(Mrows / 128, Dm / 128, 3), 256, 0, stream>>>(
      q, k, v, wq, wk, wv, bq, bk, bv, qkv, Mrows, Dm, Dm, (int)QKV_LD);

  // attention
  attn_kernel<<<dim3(Lq / 64, Bq * 16), 256, 0, stream>>>(qkv, maskp, attnout);

  // output projection -> f32
  gemm_k<true, false><<<dim3(Mrows / 128, Dm / 128, 1), 256, 0, stream>>>(
      attnout, attnout, attnout, wo, wo, wo, bo, bo, bo, d_out, Mrows, Dm, Dm, Dm);
}

// Round 3
// 316.062 us; speedup vs baseline: 1.1196x; 1.1196x over previous
//
#include <hip/hip_runtime.h>
#include <hip/hip_bf16.h>

// MultiHeadAttentionBlock on MI355X (gfx950), bf16 MFMA pipeline.
// B=2, L=2048, D=1024, H=16, DK=64.  ws: qkv 24 MiB + attnout 8 MiB = 32 MiB.

#define DEVINL __device__ __forceinline__

typedef __attribute__((ext_vector_type(8))) short short8;   // 8 x bf16 bits
typedef __attribute__((ext_vector_type(4))) float floatx4;  // MFMA C/D frag

static constexpr int Bq = 2, Lq = 2048, Dm = 1024;
static constexpr int Mrows = Bq * Lq;   // 4096
static constexpr size_t QKV_LD = 3072;  // packed Q|K|V row stride

DEVINL unsigned short f2bf(float x) {
  __hip_bfloat16 h = __float2bfloat16(x);
  unsigned short u;
  __builtin_memcpy(&u, &h, 2);
  return u;
}

DEVINL short8 cvt8(float4 a, float4 b) {
  union { unsigned short u[8]; short8 v; } o;
  o.u[0] = f2bf(a.x); o.u[1] = f2bf(a.y); o.u[2] = f2bf(a.z); o.u[3] = f2bf(a.w);
  o.u[4] = f2bf(b.x); o.u[5] = f2bf(b.y); o.u[6] = f2bf(b.z); o.u[7] = f2bf(b.w);
  return o.v;
}

DEVINL void gll16(const void* g, const void* l) {
  auto gp = (const __attribute__((address_space(1))) char*)(unsigned long long)(uintptr_t)g;
  auto lp = (__attribute__((address_space(3))) char*)(unsigned int)(uintptr_t)l;
  __builtin_amdgcn_global_load_lds(gp, lp, 16, 0, 0);
}

// ---------------- GEMM: C = A @ W^T + bias ----------------
// 128x128 tile, BK=32, 4 waves, 16x16x32 bf16 MFMA, LDS double-buffered,
// ONE barrier per K-step (loads for t+2 issued before compute of t).
template <bool A_BF16, bool OUT_BF16>
__global__ __launch_bounds__(256) void gemm_k(
    const void* __restrict__ A0, const void* __restrict__ A1, const void* __restrict__ A2,
    const float* __restrict__ W0, const float* __restrict__ W1, const float* __restrict__ W2,
    const float* __restrict__ b0, const float* __restrict__ b1, const float* __restrict__ b2,
    void* __restrict__ Cout, int M, int N, int K, int ldc) {
  const int z = blockIdx.z;
  const void* Aany = (z == 0) ? A0 : ((z == 1) ? A1 : A2);
  const float* W = (z == 0) ? W0 : ((z == 1) ? W1 : W2);
  const float* bias = (z == 0) ? b0 : ((z == 1) ? b1 : b2);
  const int m0 = blockIdx.x * 128, n0 = blockIdx.y * 128;
  const int tid = threadIdx.x, lane = tid & 63, w = tid >> 6;
  const int wr = w >> 1, wc = w & 1;

  __shared__ __align__(16) unsigned short As[2][128 * 32];
  __shared__ __align__(16) unsigned short Bs[2][128 * 32];

  floatx4 acc[4][4] = {};
  float4 wreg[2][2], areg[2][2];

  auto loadW = [&](int kt) {
#pragma unroll
    for (int it = 0; it < 2; ++it) {
      int g = it * 256 + tid, row = g >> 2, gk = g & 3;
      const float* p = W + (size_t)(n0 + row) * K + kt + gk * 8;
      wreg[it][0] = ((const float4*)p)[0];
      wreg[it][1] = ((const float4*)p)[1];
    }
  };
  auto loadA = [&](int kt) {
#pragma unroll
    for (int it = 0; it < 2; ++it) {
      int g = it * 256 + tid, row = g >> 2, gk = g & 3;
      const float* p = (const float*)Aany + (size_t)(m0 + row) * K + kt + gk * 8;
      areg[it][0] = ((const float4*)p)[0];
      areg[it][1] = ((const float4*)p)[1];
    }
  };
  auto writeW = [&](int buf) {
#pragma unroll
    for (int it = 0; it < 2; ++it) {
      int g = it * 256 + tid, row = g >> 2, gk = g & 3;
      *(short8*)((char*)Bs + buf * 8192 + row * 64 + ((gk ^ (row & 3)) << 4)) =
          cvt8(wreg[it][0], wreg[it][1]);
    }
  };
  auto writeA = [&](int buf) {
#pragma unroll
    for (int it = 0; it < 2; ++it) {
      int g = it * 256 + tid, row = g >> 2, gk = g & 3;
      *(short8*)((char*)As + buf * 8192 + row * 64 + ((gk ^ (row & 3)) << 4)) =
          cvt8(areg[it][0], areg[it][1]);
    }
  };
  auto stageA = [&](int kt, int buf) {
#pragma unroll
    for (int it = 0; it < 2; ++it) {
      int g = it * 256 + tid, row = g >> 2, gk = g & 3;
      int koff = (gk ^ (row & 3)) * 8;
      gll16((const unsigned short*)Aany + (size_t)(m0 + row) * K + kt + koff,
            (const char*)As + buf * 8192 + (it * 256 + w * 64) * 16);
    }
  };

  const int nt = K / 32;
  // prologue: stage tile 0 into buf0, issue loads for tile 1
  loadW(0);
  if (!A_BF16) loadA(0);
  writeW(0);
  if (A_BF16) stageA(0, 0); else writeA(0);
  if (nt > 1) { loadW(32); if (!A_BF16) loadA(32); }
  __syncthreads();

  const int krow = lane >> 4;
  for (int t = 0; t < nt; ++t) {
    const int c = t & 1, n = c ^ 1;
    if (t + 1 < nt) {
      // stage tile t+1 into buf n (regs loaded last iter / prologue)
      writeW(n);
      if (A_BF16) stageA((t + 1) * 32, n); else writeA(n);
      if (t + 2 < nt) { loadW((t + 2) * 32); if (!A_BF16) loadA((t + 2) * 32); }
    }
    // compute tile t from buf c
    short8 af[4], bf[4];
#pragma unroll
    for (int m = 0; m < 4; ++m) {
      int row = wr * 64 + m * 16 + (lane & 15);
      af[m] = *(const short8*)((const char*)As + c * 8192 + row * 64 + ((krow ^ (row & 3)) << 4));
    }
#pragma unroll
    for (int n2 = 0; n2 < 4; ++n2) {
      int row = wc * 64 + n2 * 16 + (lane & 15);
      bf[n2] = *(const short8*)((const char*)Bs + c * 8192 + row * 64 + ((krow ^ (row & 3)) << 4));
    }
    __builtin_amdgcn_s_setprio(1);
#pragma unroll
    for (int m = 0; m < 4; ++m)
#pragma unroll
      for (int n2 = 0; n2 < 4; ++n2)
        acc[m][n2] = __builtin_amdgcn_mfma_f32_16x16x32_bf16(af[m], bf[n2], acc[m][n2], 0, 0, 0);
    __builtin_amdgcn_s_setprio(0);
    __syncthreads();
  }

  const int r4 = lane >> 4;
#pragma unroll
  for (int m = 0; m < 4; ++m)
#pragma unroll
    for (int n2 = 0; n2 < 4; ++n2) {
      int col = n0 + wc * 64 + n2 * 16 + (lane & 15);
      float bv = bias[col];
#pragma unroll
      for (int r = 0; r < 4; ++r) {
        int row = m0 + wr * 64 + m * 16 + r4 * 4 + r;
        float v = acc[m][n2][r] + bv;
        if (OUT_BF16)
          ((unsigned short*)Cout)[(size_t)row * ldc + (size_t)z * N + col] = f2bf(v);
        else
          ((float*)Cout)[(size_t)row * ldc + (size_t)z * N + col] = v;
      }
    }
}

// ---------------- flash attention ----------------
// grid (L/64, B*H), 4 waves; wave w owns q rows [q0+16w, q0+16w+16).
// Double-buffered K (gll16) and Vt (reg-staged, bank-bijective u32 writes);
// one barrier per key-tile; loads issued at iter top hide under compute.
__global__ __launch_bounds__(256) void attn_kernel(const unsigned short* __restrict__ QKV,
                                                   const int* __restrict__ mask,
                                                   unsigned short* __restrict__ Aout) {
  const int bh = blockIdx.y, b = bh >> 4, h = bh & 15;
  const int q0 = blockIdx.x * 64;
  const int tid = threadIdx.x, lane = tid & 63, w = tid >> 6;

  __shared__ __align__(16) unsigned short Klds[2][64 * 64];   // 16 KB
  __shared__ __align__(16) unsigned short Vtlds[2][64 * 64];  // 16 KB
  __shared__ __align__(16) unsigned short Plds[4][16 * 64];   // 8 KB (XOR-swizzled)

  const unsigned short* base = QKV + (size_t)b * Lq * QKV_LD;
  const unsigned short* Kbase = base + 1024;
  const unsigned short* Vbase = base + 2048;

  // Q fragments
  short8 qf[2];
  {
    int row = q0 + w * 16 + (lane & 15);
#pragma unroll
    for (int c = 0; c < 2; ++c)
      qf[c] = *(const short8*)(base + (size_t)row * QKV_LD + h * 64 + c * 32 + (lane >> 4) * 8);
  }

  const int kp = tid & 31;         // key-pair index (keys 2kp, 2kp+1)
  const int vd0 = (tid >> 5) * 8;  // d-chunk base

  auto stageK = [&](int t, int buf) {
#pragma unroll
    for (int it = 0; it < 2; ++it) {
      int g = it * 256 + tid, key = g >> 3, gk = g & 7;
      gll16(Kbase + (size_t)(t * 64 + key) * QKV_LD + h * 64 + (gk ^ (key & 7)) * 8,
            (const char*)Klds + buf * 8192 + (it * 256 + w * 64) * 16);
    }
  };
  short8 vr0, vr1;
  auto loadV = [&](int t) {
    vr0 = *(const short8*)(Vbase + (size_t)(t * 64 + 2 * kp) * QKV_LD + h * 64 + vd0);
    vr1 = *(const short8*)(Vbase + (size_t)(t * 64 + 2 * kp + 1) * QKV_LD + h * 64 + vd0);
  };
  auto writeV = [&](int buf) {
#pragma unroll
    for (int i = 0; i < 8; ++i) {
      int d = vd0 + i;
      unsigned int val = (unsigned int)(unsigned short)vr0[i] |
                         ((unsigned int)(unsigned short)vr1[i] << 16);
      *(unsigned int*)((char*)Vtlds + buf * 8192 + d * 128 + (((kp >> 2) ^ (d & 7)) << 4) +
                       (kp & 3) * 4) = val;
    }
  };

  // prologue: tile 0 into buf 0
  stageK(0, 0);
  loadV(0);
  writeV(0);
  __syncthreads();

  floatx4 o[4] = {};
  float mrow[4], lrow[4];
#pragma unroll
  for (int r = 0; r < 4; ++r) { mrow[r] = -1e30f; lrow[r] = 0.f; }

  for (int t = 0; t < Lq / 64; ++t) {
    const int c = t & 1, n = c ^ 1;
    if (t + 1 < Lq / 64) { stageK(t + 1, n); loadV(t + 1); }

    // S = Q K^T (16 q x 64 keys per wave)
    floatx4 s[4] = {};
    __builtin_amdgcn_s_setprio(1);
#pragma unroll
    for (int f = 0; f < 4; ++f) {
      int key = f * 16 + (lane & 15);
#pragma unroll
      for (int c2 = 0; c2 < 2; ++c2) {
        short8 kf = *(const short8*)((const char*)Klds + c * 8192 + key * 128 +
                                     (((c2 * 4 + (lane >> 4)) ^ (key & 7)) << 4));
        s[f] = __builtin_amdgcn_mfma_f32_16x16x32_bf16(qf[c2], kf, s[f], 0, 0, 0);
      }
    }
    __builtin_amdgcn_s_setprio(0);

    // scale + mask + online softmax
    float tmax[4] = {-1e30f, -1e30f, -1e30f, -1e30f};
#pragma unroll
    for (int f = 0; f < 4; ++f) {
      int mv = mask[b * Lq + t * 64 + f * 16 + (lane & 15)];
#pragma unroll
      for (int r = 0; r < 4; ++r) {
        float sv = s[f][r] * 0.125f;
        sv = mv ? sv : -1e9f;
        s[f][r] = sv;
        tmax[r] = fmaxf(tmax[r], sv);
      }
    }
#pragma unroll
    for (int dx = 1; dx <= 8; dx <<= 1)
#pragma unroll
      for (int r = 0; r < 4; ++r) tmax[r] = fmaxf(tmax[r], __shfl_xor(tmax[r], dx, 64));

    float mnew[4], alpha[4], rsum[4] = {0, 0, 0, 0};
#pragma unroll
    for (int r = 0; r < 4; ++r) {
      mnew[r] = fmaxf(mrow[r], tmax[r]);
      alpha[r] = __expf(mrow[r] - mnew[r]);
      mrow[r] = mnew[r];
    }
#pragma unroll
    for (int f = 0; f < 4; ++f)
#pragma unroll
      for (int r = 0; r < 4; ++r) {
        float p = __expf(s[f][r] - mnew[r]);
        s[f][r] = p;
        rsum[r] += p;
      }
#pragma unroll
    for (int dx = 1; dx <= 8; dx <<= 1)
#pragma unroll
      for (int r = 0; r < 4; ++r) rsum[r] += __shfl_xor(rsum[r], dx, 64);
#pragma unroll
    for (int r = 0; r < 4; ++r) lrow[r] = lrow[r] * alpha[r] + rsum[r];
#pragma unroll
    for (int df = 0; df < 4; ++df)
#pragma unroll
      for (int r = 0; r < 4; ++r) o[df][r] *= alpha[r];

    // P -> LDS (bf16), XOR-swizzled, wave-private (no barrier needed)
#pragma unroll
    for (int f = 0; f < 4; ++f)
#pragma unroll
      for (int r = 0; r < 4; ++r) {
        int row = (lane >> 4) * 4 + r, col = f * 16 + (lane & 15);
        *(unsigned short*)((char*)&Plds[w][0] + row * 128 + (((col >> 3) ^ (row & 7)) << 4) +
                           (col & 7) * 2) = f2bf(s[f][r]);
      }

    // O += P @ V
    short8 pf[2];
#pragma unroll
    for (int kc = 0; kc < 2; ++kc)
      pf[kc] = *(const short8*)((const char*)&Plds[w][0] + (lane & 15) * 128 +
                                (((kc * 4 + (lane >> 4)) ^ (lane & 7)) << 4));
    __builtin_amdgcn_s_setprio(1);
#pragma unroll
    for (int df = 0; df < 4; ++df) {
      int d = df * 16 + (lane & 15);
#pragma unroll
      for (int kc = 0; kc < 2; ++kc) {
        short8 vf = *(const short8*)((const char*)Vtlds + c * 8192 + d * 128 +
                                     (((kc * 4 + (lane >> 4)) ^ (d & 7)) << 4));
        o[df] = __builtin_amdgcn_mfma_f32_16x16x32_bf16(pf[kc], vf, o[df], 0, 0, 0);
      }
    }
    __builtin_amdgcn_s_setprio(0);

    if (t + 1 < Lq / 64) writeV(n);  // V[t+1] regs -> Vt buf n
    __syncthreads();
  }

  // normalize + store bf16
#pragma unroll
  for (int df = 0; df < 4; ++df)
#pragma unroll
    for (int r = 0; r < 4; ++r) {
      int row = q0 + w * 16 + (lane >> 4) * 4 + r;
      int col = h * 64 + df * 16 + (lane & 15);
      Aout[(size_t)(b * Lq + row) * Dm + col] = f2bf(o[df][r] / lrow[r]);
    }
}

// ---------------- launcher ----------------
extern "C" void kernel_launch(void* const* d_in, const int* in_sizes, int n_in,
                              void* d_out, int out_size, void* d_ws, size_t ws_size,
                              hipStream_t stream) {
  const float* q = (const float*)d_in[0];
  const float* k = (const float*)d_in[1];
  const float* v = (const float*)d_in[2];
  const int* maskp = (const int*)d_in[3];
  const float* wq = (const float*)d_in[4];
  const float* bq = (const float*)d_in[5];
  const float* wk = (const float*)d_in[6];
  const float* bk = (const float*)d_in[7];
  const float* wv = (const float*)d_in[8];
  const float* bv = (const float*)d_in[9];
  const float* wo = (const float*)d_in[10];
  const float* bo = (const float*)d_in[11];

  unsigned short* qkv = (unsigned short*)d_ws;             // 24 MiB
  unsigned short* attnout = qkv + (size_t)Mrows * QKV_LD;  // 8 MiB

  gemm_k<false, true><<<dim3(Mrows / 128, Dm / 128, 3), 256, 0, stream>>>(
      q, k, v, wq, wk, wv, bq, bk, bv, qkv, Mrows, Dm, Dm, (int)QKV_LD);

  attn_kernel<<<dim3(Lq / 64, Bq * 16), 256, 0, stream>>>(qkv, maskp, attnout);

  gemm_k<true, false><<<dim3(Mrows / 128, Dm / 128, 1), 256, 0, stream>>>(
      attnout, attnout, attnout, wo, wo, wo, bo, bo, bo, d_out, Mrows, Dm, Dm, Dm);
}

// Round 4
// 276.307 us; speedup vs baseline: 1.2807x; 1.1439x over previous
//
#include <hip/hip_runtime.h>
#include <hip/hip_bf16.h>

// MultiHeadAttentionBlock on MI355X (gfx950), bf16 MFMA pipeline.
// B=2, L=2048, D=1024, H=16, DK=64.  ws: qkv 24 MiB + attnout 8 MiB = 32 MiB.

#define DEVINL __device__ __forceinline__

typedef __attribute__((ext_vector_type(8))) short short8;   // 8 x bf16 bits
typedef __attribute__((ext_vector_type(4))) float floatx4;  // MFMA C/D frag

static constexpr int Bq = 2, Lq = 2048, Dm = 1024;
static constexpr int Mrows = Bq * Lq;   // 4096
static constexpr size_t QKV_LD = 3072;  // packed Q|K|V row stride
static constexpr int NT = Lq / 64;      // 32 key tiles

DEVINL unsigned short f2bf(float x) {
  __hip_bfloat16 h = __float2bfloat16(x);
  unsigned short u;
  __builtin_memcpy(&u, &h, 2);
  return u;
}

DEVINL float bf2f(unsigned short u) {
  unsigned int t = ((unsigned int)u) << 16;
  float f;
  __builtin_memcpy(&f, &t, 4);
  return f;
}

DEVINL short8 cvt8(float4 a, float4 b) {
  union { unsigned short u[8]; short8 v; } o;
  o.u[0] = f2bf(a.x); o.u[1] = f2bf(a.y); o.u[2] = f2bf(a.z); o.u[3] = f2bf(a.w);
  o.u[4] = f2bf(b.x); o.u[5] = f2bf(b.y); o.u[6] = f2bf(b.z); o.u[7] = f2bf(b.w);
  return o.v;
}

DEVINL void gll16(const void* g, const void* l) {
  auto gp = (const __attribute__((address_space(1))) char*)(unsigned long long)(uintptr_t)g;
  auto lp = (__attribute__((address_space(3))) char*)(unsigned int)(uintptr_t)l;
  __builtin_amdgcn_global_load_lds(gp, lp, 16, 0, 0);
}

// ---------------- GEMM: C = A @ W^T + bias ----------------
// 128x128 tile, BK=32, 4 waves, LDS double-buffered, one barrier per K-step.
// Order: frag-read+MFMA(buf c) FIRST, then stage buf n from regs (loads issued
// a full iteration earlier -> HBM latency hidden under compute), then prefetch.
template <bool A_BF16, bool OUT_BF16>
__global__ __launch_bounds__(256) void gemm_k(
    const void* __restrict__ A0, const void* __restrict__ A1, const void* __restrict__ A2,
    const float* __restrict__ W0, const float* __restrict__ W1, const float* __restrict__ W2,
    const float* __restrict__ b0, const float* __restrict__ b1, const float* __restrict__ b2,
    void* __restrict__ Cout, int M, int N, int K, int ldc) {
  const int z = blockIdx.z;
  const void* Aany = (z == 0) ? A0 : ((z == 1) ? A1 : A2);
  const float* W = (z == 0) ? W0 : ((z == 1) ? W1 : W2);
  const float* bias = (z == 0) ? b0 : ((z == 1) ? b1 : b2);
  const int m0 = blockIdx.x * 128, n0 = blockIdx.y * 128;
  const int tid = threadIdx.x, lane = tid & 63, w = tid >> 6;
  const int wr = w >> 1, wc = w & 1;

  __shared__ __align__(16) unsigned short As[2][128 * 32];
  __shared__ __align__(16) unsigned short Bs[2][128 * 32];

  floatx4 acc[4][4] = {};
  float4 wreg[2][2], areg[2][2];

  auto loadW = [&](int kt) {
#pragma unroll
    for (int it = 0; it < 2; ++it) {
      int g = it * 256 + tid, row = g >> 2, gk = g & 3;
      const float* p = W + (size_t)(n0 + row) * K + kt + gk * 8;
      wreg[it][0] = ((const float4*)p)[0];
      wreg[it][1] = ((const float4*)p)[1];
    }
  };
  auto loadA = [&](int kt) {
#pragma unroll
    for (int it = 0; it < 2; ++it) {
      int g = it * 256 + tid, row = g >> 2, gk = g & 3;
      const float* p = (const float*)Aany + (size_t)(m0 + row) * K + kt + gk * 8;
      areg[it][0] = ((const float4*)p)[0];
      areg[it][1] = ((const float4*)p)[1];
    }
  };
  auto writeW = [&](int buf) {
#pragma unroll
    for (int it = 0; it < 2; ++it) {
      int g = it * 256 + tid, row = g >> 2, gk = g & 3;
      *(short8*)((char*)Bs + buf * 8192 + row * 64 + ((gk ^ (row & 3)) << 4)) =
          cvt8(wreg[it][0], wreg[it][1]);
    }
  };
  auto writeA = [&](int buf) {
#pragma unroll
    for (int it = 0; it < 2; ++it) {
      int g = it * 256 + tid, row = g >> 2, gk = g & 3;
      *(short8*)((char*)As + buf * 8192 + row * 64 + ((gk ^ (row & 3)) << 4)) =
          cvt8(areg[it][0], areg[it][1]);
    }
  };
  auto stageA = [&](int kt, int buf) {
#pragma unroll
    for (int it = 0; it < 2; ++it) {
      int g = it * 256 + tid, row = g >> 2, gk = g & 3;
      int koff = (gk ^ (row & 3)) * 8;
      gll16((const unsigned short*)Aany + (size_t)(m0 + row) * K + kt + koff,
            (const char*)As + buf * 8192 + (it * 256 + w * 64) * 16);
    }
  };

  const int nt = K / 32;
  // prologue: stage tile 0 -> buf0; issue loads for tile 1
  loadW(0);
  if (!A_BF16) loadA(0);
  writeW(0);
  if (A_BF16) stageA(0, 0); else writeA(0);
  if (nt > 1) { loadW(32); if (!A_BF16) loadA(32); }
  __syncthreads();

  const int krow = lane >> 4;
  for (int t = 0; t < nt; ++t) {
    const int c = t & 1, n = c ^ 1;
    // compute tile t from buf c
    short8 af[4], bfr[4];
#pragma unroll
    for (int m = 0; m < 4; ++m) {
      int row = wr * 64 + m * 16 + (lane & 15);
      af[m] = *(const short8*)((const char*)As + c * 8192 + row * 64 + ((krow ^ (row & 3)) << 4));
    }
#pragma unroll
    for (int n2 = 0; n2 < 4; ++n2) {
      int row = wc * 64 + n2 * 16 + (lane & 15);
      bfr[n2] = *(const short8*)((const char*)Bs + c * 8192 + row * 64 + ((krow ^ (row & 3)) << 4));
    }
    __builtin_amdgcn_s_setprio(1);
#pragma unroll
    for (int m = 0; m < 4; ++m)
#pragma unroll
      for (int n2 = 0; n2 < 4; ++n2)
        acc[m][n2] = __builtin_amdgcn_mfma_f32_16x16x32_bf16(af[m], bfr[n2], acc[m][n2], 0, 0, 0);
    __builtin_amdgcn_s_setprio(0);
    // stage tile t+1 into buf n (regs were loaded one full iteration ago)
    if (t + 1 < nt) {
      writeW(n);
      if (A_BF16) stageA((t + 1) * 32, n); else writeA(n);
      if (t + 2 < nt) { loadW((t + 2) * 32); if (!A_BF16) loadA((t + 2) * 32); }
    }
    __syncthreads();
  }

  const int r4 = lane >> 4;
#pragma unroll
  for (int m = 0; m < 4; ++m)
#pragma unroll
    for (int n2 = 0; n2 < 4; ++n2) {
      int col = n0 + wc * 64 + n2 * 16 + (lane & 15);
      float bv = bias[col];
#pragma unroll
      for (int r = 0; r < 4; ++r) {
        int row = m0 + wr * 64 + m * 16 + r4 * 4 + r;
        float v = acc[m][n2][r] + bv;
        if (OUT_BF16)
          ((unsigned short*)Cout)[(size_t)row * ldc + (size_t)z * N + col] = f2bf(v);
        else
          ((float*)Cout)[(size_t)row * ldc + (size_t)z * N + col] = v;
      }
    }
}

// ---------------- flash attention ----------------
// grid (L/64, B*H), 4 waves; wave w owns q rows [q0+16w, q0+16w+16).
// K/Vt double-buffered, one barrier per tile. Softmax: scale folded into Q,
// per-tile all-ones mask flags, defer-max (skip rescale+max-reduce), row-sum
// via mfma(P, ones) accumulated across tiles in the o-frag layout.
__global__ __launch_bounds__(256) void attn_kernel(const unsigned short* __restrict__ QKV,
                                                   const int* __restrict__ mask,
                                                   unsigned short* __restrict__ Aout) {
  const int bh = blockIdx.y, b = bh >> 4, h = bh & 15;
  const int q0 = blockIdx.x * 64;
  const int tid = threadIdx.x, lane = tid & 63, w = tid >> 6;

  __shared__ __align__(16) unsigned short Klds[2][64 * 64];   // 16 KB
  __shared__ __align__(16) unsigned short Vtlds[2][64 * 64];  // 16 KB
  __shared__ __align__(16) unsigned short Plds[4][16 * 64];   // 8 KB (XOR-swizzled)
  __shared__ int mflag[NT];

  const unsigned short* base = QKV + (size_t)b * Lq * QKV_LD;
  const unsigned short* Kbase = base + 1024;
  const unsigned short* Vbase = base + 2048;

  const int kp = tid & 31;         // key-pair index
  const int vd0 = (tid >> 5) * 8;  // d-chunk base

  auto stageK = [&](int t, int buf) {
#pragma unroll
    for (int it = 0; it < 2; ++it) {
      int g = it * 256 + tid, key = g >> 3, gk = g & 7;
      gll16(Kbase + (size_t)(t * 64 + key) * QKV_LD + h * 64 + (gk ^ (key & 7)) * 8,
            (const char*)Klds + buf * 8192 + (it * 256 + w * 64) * 16);
    }
  };
  short8 vr0, vr1;
  auto loadV = [&](int t) {
    vr0 = *(const short8*)(Vbase + (size_t)(t * 64 + 2 * kp) * QKV_LD + h * 64 + vd0);
    vr1 = *(const short8*)(Vbase + (size_t)(t * 64 + 2 * kp + 1) * QKV_LD + h * 64 + vd0);
  };
  auto writeV = [&](int buf) {
#pragma unroll
    for (int i = 0; i < 8; ++i) {
      int d = vd0 + i;
      unsigned int val = (unsigned int)(unsigned short)vr0[i] |
                         ((unsigned int)(unsigned short)vr1[i] << 16);
      *(unsigned int*)((char*)Vtlds + buf * 8192 + d * 128 + (((kp >> 2) ^ (d & 7)) << 4) +
                       (kp & 3) * 4) = val;
    }
  };

  // prologue: stage tile 0; compute per-tile mask all-ones flags
  stageK(0, 0);
  loadV(0);
  writeV(0);
  {
    const int* mp = mask + b * Lq + tid * 8;
    int4 a = ((const int4*)mp)[0], bb = ((const int4*)mp)[1];
    int myall = (a.x && a.y && a.z && a.w && bb.x && bb.y && bb.z && bb.w) ? 1 : 0;
    unsigned long long bal = __ballot(myall);
    if (lane < 8) mflag[w * 8 + lane] = (((bal >> (lane * 8)) & 0xffull) == 0xffull);
  }

  // Q fragments, pre-scaled by 1/sqrt(dk)=0.125 (exact in bf16)
  short8 qf[2];
  {
    int row = q0 + w * 16 + (lane & 15);
#pragma unroll
    for (int c = 0; c < 2; ++c) {
      short8 raw = *(const short8*)(base + (size_t)row * QKV_LD + h * 64 + c * 32 + (lane >> 4) * 8);
      union { unsigned short u[8]; short8 v; } o2;
#pragma unroll
      for (int i = 0; i < 8; ++i) o2.u[i] = f2bf(bf2f((unsigned short)raw[i]) * 0.125f);
      qf[c] = o2.v;
    }
  }
  union { unsigned short u[8]; short8 v; } one_u;
#pragma unroll
  for (int i = 0; i < 8; ++i) one_u.u[i] = 0x3F80;  // bf16 1.0
  const short8 ones8 = one_u.v;

  __syncthreads();

  floatx4 o[4] = {};
  floatx4 lacc = {};
  float mrow[4];
#pragma unroll
  for (int r = 0; r < 4; ++r) mrow[r] = -1e30f;

  for (int t = 0; t < NT; ++t) {
    const int c = t & 1, n = c ^ 1;
    if (t + 1 < NT) { stageK(t + 1, n); loadV(t + 1); }

    // S = Q K^T (16 q x 64 keys per wave), already scaled
    floatx4 s[4] = {};
    __builtin_amdgcn_s_setprio(1);
#pragma unroll
    for (int f = 0; f < 4; ++f) {
      int key = f * 16 + (lane & 15);
#pragma unroll
      for (int c2 = 0; c2 < 2; ++c2) {
        short8 kf = *(const short8*)((const char*)Klds + c * 8192 + key * 128 +
                                     (((c2 * 4 + (lane >> 4)) ^ (key & 7)) << 4));
        s[f] = __builtin_amdgcn_mfma_f32_16x16x32_bf16(qf[c2], kf, s[f], 0, 0, 0);
      }
    }
    __builtin_amdgcn_s_setprio(0);

    // per-lane partial row max (over f)
    float tmax[4];
#pragma unroll
    for (int r = 0; r < 4; ++r)
      tmax[r] = fmaxf(fmaxf(s[0][r], s[1][r]), fmaxf(s[2][r], s[3][r]));
    const int allm = mflag[t];
    bool ok = (tmax[0] <= mrow[0] + 8.f) && (tmax[1] <= mrow[1] + 8.f) &&
              (tmax[2] <= mrow[2] + 8.f) && (tmax[3] <= mrow[3] + 8.f);
    if (__ballot(ok && allm) == ~0ull) {
      // fast path: no rescale, no max-reduce, no mask
#pragma unroll
      for (int f = 0; f < 4; ++f)
#pragma unroll
        for (int r = 0; r < 4; ++r) s[f][r] = __expf(s[f][r] - mrow[r]);
    } else {
      // full path: reduce max across the 16 key-lanes
#pragma unroll
      for (int dx = 1; dx <= 8; dx <<= 1)
#pragma unroll
        for (int r = 0; r < 4; ++r) tmax[r] = fmaxf(tmax[r], __shfl_xor(tmax[r], dx, 64));
      float mnew[4], alpha[4];
#pragma unroll
      for (int r = 0; r < 4; ++r) {
        mnew[r] = fmaxf(mrow[r], tmax[r]);
        alpha[r] = __expf(mrow[r] - mnew[r]);
        mrow[r] = mnew[r];
      }
#pragma unroll
      for (int df = 0; df < 4; ++df)
#pragma unroll
        for (int r = 0; r < 4; ++r) o[df][r] *= alpha[r];
#pragma unroll
      for (int r = 0; r < 4; ++r) lacc[r] *= alpha[r];
      if (allm) {
#pragma unroll
        for (int f = 0; f < 4; ++f)
#pragma unroll
          for (int r = 0; r < 4; ++r) s[f][r] = __expf(s[f][r] - mnew[r]);
      } else {
#pragma unroll
        for (int f = 0; f < 4; ++f) {
          int mv = mask[b * Lq + t * 64 + f * 16 + (lane & 15)];
#pragma unroll
          for (int r = 0; r < 4; ++r)
            s[f][r] = mv ? __expf(s[f][r] - mnew[r]) : 0.f;
        }
      }
    }

    // P -> LDS (bf16), XOR-swizzled, wave-private
#pragma unroll
    for (int f = 0; f < 4; ++f)
#pragma unroll
      for (int r = 0; r < 4; ++r) {
        int row = (lane >> 4) * 4 + r, col = f * 16 + (lane & 15);
        *(unsigned short*)((char*)&Plds[w][0] + row * 128 + (((col >> 3) ^ (row & 7)) << 4) +
                           (col & 7) * 2) = f2bf(s[f][r]);
      }

    // O += P @ V ; l += P @ ones
    short8 pf[2];
#pragma unroll
    for (int kc = 0; kc < 2; ++kc)
      pf[kc] = *(const short8*)((const char*)&Plds[w][0] + (lane & 15) * 128 +
                                (((kc * 4 + (lane >> 4)) ^ (lane & 7)) << 4));
    __builtin_amdgcn_s_setprio(1);
    lacc = __builtin_amdgcn_mfma_f32_16x16x32_bf16(pf[0], ones8, lacc, 0, 0, 0);
    lacc = __builtin_amdgcn_mfma_f32_16x16x32_bf16(pf[1], ones8, lacc, 0, 0, 0);
#pragma unroll
    for (int df = 0; df < 4; ++df) {
      int d = df * 16 + (lane & 15);
#pragma unroll
      for (int kc = 0; kc < 2; ++kc) {
        short8 vf = *(const short8*)((const char*)Vtlds + c * 8192 + d * 128 +
                                     (((kc * 4 + (lane >> 4)) ^ (d & 7)) << 4));
        o[df] = __builtin_amdgcn_mfma_f32_16x16x32_bf16(pf[kc], vf, o[df], 0, 0, 0);
      }
    }
    __builtin_amdgcn_s_setprio(0);

    if (t + 1 < NT) writeV(n);
    __syncthreads();
  }

  // normalize + store bf16
  float rl[4];
#pragma unroll
  for (int r = 0; r < 4; ++r) rl[r] = 1.0f / lacc[r];
#pragma unroll
  for (int df = 0; df < 4; ++df)
#pragma unroll
    for (int r = 0; r < 4; ++r) {
      int row = q0 + w * 16 + (lane >> 4) * 4 + r;
      int col = h * 64 + df * 16 + (lane & 15);
      Aout[(size_t)(b * Lq + row) * Dm + col] = f2bf(o[df][r] * rl[r]);
    }
}

// ---------------- launcher ----------------
extern "C" void kernel_launch(void* const* d_in, const int* in_sizes, int n_in,
                              void* d_out, int out_size, void* d_ws, size_t ws_size,
                              hipStream_t stream) {
  const float* q = (const float*)d_in[0];
  const float* k = (const float*)d_in[1];
  const float* v = (const float*)d_in[2];
  const int* maskp = (const int*)d_in[3];
  const float* wq = (const float*)d_in[4];
  const float* bq = (const float*)d_in[5];
  const float* wk = (const float*)d_in[6];
  const float* bk = (const float*)d_in[7];
  const float* wv = (const float*)d_in[8];
  const float* bv = (const float*)d_in[9];
  const float* wo = (const float*)d_in[10];
  const float* bo = (const float*)d_in[11];

  unsigned short* qkv = (unsigned short*)d_ws;             // 24 MiB
  unsigned short* attnout = qkv + (size_t)Mrows * QKV_LD;  // 8 MiB

  gemm_k<false, true><<<dim3(Mrows / 128, Dm / 128, 3), 256, 0, stream>>>(
      q, k, v, wq, wk, wv, bq, bk, bv, qkv, Mrows, Dm, Dm, (int)QKV_LD);

  attn_kernel<<<dim3(Lq / 64, Bq * 16), 256, 0, stream>>>(qkv, maskp, attnout);

  gemm_k<true, false><<<dim3(Mrows / 128, Dm / 128, 1), 256, 0, stream>>>(
      attnout, attnout, attnout, wo, wo, wo, bo, bo, bo, d_out, Mrows, Dm, Dm, Dm);
}